// Round 2
// baseline (488.152 us; speedup 1.0000x reference)
//
#include <hip/hip_runtime.h>

// Problem constants (B=64, C=D=64, H=W=64, K=1024)
#define K_CODES 1024
#define D_DIM   64
#define N_ROWS  262144      // B*H*W
#define HW      4096        // H*W
#define CHW     262144      // C*H*W
#define N_ELEM  16777216    // B*C*H*W
#define DECAY   0.99f
#define OMD     0.01f       // 1 - DECAY
#define EPS_F   1e-05f
// Margin = 40 sigma of split-bf16 score noise (~1e-4) + 64-ULP j-packing
// perturbation (<=0.001 for |s|<256). Near-ties under this margin go to refine.
#define MARGIN_BF 0.008f
#define FLAG_CAP 32768      // expected flags ~500 (0.2%)
#define SEG_CAP  2048       // per-code row cap (mean 256, Poisson max ~340)
#define NHB      64         // hist blocks (4096 rows each)
#define BROWS    128        // rows per argmin block (32 per wave)

typedef __attribute__((ext_vector_type(8))) short bf16x8;  // 8 bf16 = 4 VGPRs
typedef __attribute__((ext_vector_type(4))) float f32x4;

// Workspace layout (bytes); [0,64) is the only zeroed region. All 16B-aligned.
// FLAGS and WFRAG temporally overlay SORT (dead before scatter writes it).
constexpr size_t OFF_LOSS    = 0;        // 1 double
constexpr size_t OFF_FLAGCNT = 8;        // 1 int
constexpr size_t OFF_DONE    = 12;       // 1 int (out_kernel completion count)
constexpr size_t ZERO_BYTES  = 64;
constexpr size_t OFF_W2F     = 64;       // 1024 f   -> 4160
constexpr size_t OFF_W2D     = 4160;     // 1024 d   -> 12352
constexpr size_t OFF_CS     = 12352;     // 1024 f   -> 16448
constexpr size_t OFF_GOFF    = 16448;    // 1025 i   -> 20608 (padded)
constexpr size_t OFF_DW      = 20608;    // 65536 f  -> 282752 (unused, kept)
constexpr size_t OFF_NEWW    = 282752;   // 65536 f  -> 544896
constexpr size_t OFF_IDX     = 544896;   // 262144 i -> 1593472
constexpr size_t OFF_HISTB   = 1593472;  // 64x1024 i -> 1855616
constexpr size_t OFF_SORT    = 1855616;  // 262144 i -> 2904192
constexpr size_t OFF_FLAGS   = 1855616;  // 32768 i (dead after refine)
constexpr size_t OFF_WFRAG   = 1986688;  // 131072 bf16 (dead after argmin) -> 2248832

__device__ __forceinline__ short f2bf(float f) {  // RNE float->bf16
    unsigned u = __float_as_uint(f);
    u += 0x7fffu + ((u >> 16) & 1u);
    return (short)(u >> 16);
}
__device__ __forceinline__ float bf2f(short h) {
    return __uint_as_float(((unsigned)(unsigned short)h) << 16);
}

// Async global->LDS, 16B per lane. LDS dest is wave-uniform base + lane*16
// (hardware semantics); our dest layout is linear in thread id so this holds.
__device__ __forceinline__ void gload_lds16(const float4* g, void* l) {
    __builtin_amdgcn_global_load_lds(
        (const __attribute__((address_space(1))) void*)g,
        (__attribute__((address_space(3))) void*)l, 16, 0, 0);
}

// One-time prep: W swizzled to bf16 hi/lo B-fragment pairs for 16x16x32 MFMA.
__global__ __launch_bounds__(256) void prep_kernel(
    const float* __restrict__ w, short* __restrict__ wfrag,
    float* __restrict__ w2f, double* __restrict__ w2d) {
    int t = threadIdx.x;
    if (blockIdx.x < 32) {
        int gid = blockIdx.x * 256 + t;  // (j<<7)|(h<<6)|L
        int j = gid >> 7, h = (gid >> 6) & 1, L = gid & 63;
        int code = j * 16 + (L & 15);
        int kb = h * 32 + ((L >> 4) << 3);
        const float* wp = w + code * D_DIM + kb;
        short hi[8], lo[8];
#pragma unroll
        for (int i = 0; i < 8; ++i) {
            float v = wp[i];
            short hb = f2bf(v);
            hi[i] = hb;
            lo[i] = f2bf(v - bf2f(hb));
        }
        short* dh = wfrag + (size_t)(((j * 2 + h) * 2 + 0) * 64 + L) * 8;
        short* dl = wfrag + (size_t)(((j * 2 + h) * 2 + 1) * 64 + L) * 8;
#pragma unroll
        for (int i = 0; i < 8; ++i) { dh[i] = hi[i]; dl[i] = lo[i]; }
    } else {
        int k = (blockIdx.x - 32) * 256 + t;
        const float* wk = w + k * D_DIM;
        float sf = 0.f; double sd = 0.0;
#pragma unroll
        for (int d = 0; d < D_DIM; ++d) {
            float wv = wk[d];
            sf = fmaf(wv, wv, sf);
            sd = fma((double)wv, (double)wv, sd);
        }
        w2f[k] = sf; w2d[k] = sd;
    }
}

// Split-bf16 MFMA argmin. R8 restructure: 32 rows/wave (128/block, 2048 blocks)
// — halves per-row LDS B-fragment traffic (was the largest per-CU cycle
// consumer at ~82 us: each wave reads all 256KB of wfrag from LDS regardless
// of row count). Two independent accumulator chains per jj also double MFMA
// ILP. Min-tracking packs the 6-bit supertile index j into the low mantissa
// bits of the score (pure fminf tracking, no cmp/cndmask); the <=64-ULP
// perturbation is covered by MARGIN_BF + fp64 refine (which also restores
// exact min-index tie-breaks).
// LDS = 4K (w2s) + 34816 (xs union bufB) + 16K (bufA) = 55296B -> 2 blocks/CU.
__global__ __launch_bounds__(256) __attribute__((amdgpu_waves_per_eu(2, 4)))
void argmin_kernel(
    const float* __restrict__ inp, const short* __restrict__ wfrag,
    const float* __restrict__ w2f, int* __restrict__ idx_ws,
    float* __restrict__ out_idx_f, float* __restrict__ xt,
    int* __restrict__ flagcnt, int* __restrict__ flaglist) {
    __shared__ float w2s[K_CODES];
    __shared__ alignas(16) char smem_u[BROWS * 68 * 4];  // xs(34816B) / bufB(16KB) union
    __shared__ alignas(16) short bufA[8192];             // 16 KB
    float (*xs)[68] = (float (*)[68])smem_u;             // +4 pad per row
    short* bufB = (short*)smem_u;

    int t = threadIdx.x;
    ((float4*)w2s)[t] = ((const float4*)w2f)[t];

    int rowbase = blockIdx.x * BROWS;
    int b = rowbase >> 12, hwb = rowbase & (HW - 1);
    const float* xp = inp + (size_t)b * CHW + hwb;
    int lane = t & 63, wave = t >> 6;

    // Stage x: per iteration, 2 d-values x 128 rows (coalesced 512B runs).
    int sr = t & 127, sd = t >> 7;
#pragma unroll
    for (int it = 0; it < 32; ++it) {
        int d = it * 2 + sd;
        xs[sr][d] = xp[(size_t)d * HW + sr];
    }
    __syncthreads();

    // xt side-product: coalesced row-major dump of this block's 128 rows
    float4* xt4 = (float4*)(xt + (size_t)rowbase * D_DIM);
#pragma unroll
    for (int i2 = 0; i2 < 8; ++i2) {
        int c2 = t + i2 * 256;
        xt4[c2] = ((const float4*)xs[c2 >> 4])[c2 & 15];
    }

    int q = lane >> 4, col = lane & 15;
    int wavebase = wave * 32;
    bf16x8 aH[2][2], aL[2][2];  // [row-set][k-half]
#pragma unroll
    for (int s2 = 0; s2 < 2; ++s2) {
        int rl = wavebase + s2 * 16 + col;  // A row m = lane&15
#pragma unroll
        for (int h = 0; h < 2; ++h) {
#pragma unroll
            for (int i = 0; i < 8; ++i) {
                float v = xs[rl][h * 32 + q * 8 + i];
                short hb = f2bf(v);
                aH[s2][h][i] = hb;
                aL[s2][h][i] = f2bf(v - bf2f(hb));
            }
        }
    }

    float best[2][4], best2[2][4];
#pragma unroll
    for (int s2 = 0; s2 < 2; ++s2)
#pragma unroll
        for (int r = 0; r < 4; ++r) { best[s2][r] = 3.4e38f; best2[s2][r] = 3.4e38f; }
    const float4* wsrc = (const float4*)wfrag;

    // Prologue: issue supertile 0 into bufA. xs is still live here; bufB (its
    // alias) is first written at st=0 AFTER the loop-top barrier, by which
    // point all waves have finished the fragment build + xt dump above.
    {
        const float4* src = wsrc + t;
        char* nb = (char*)bufA + wave * 1024;
#pragma unroll
        for (int i2 = 0; i2 < 4; ++i2)
            gload_lds16(src + i2 * 256, nb + i2 * 4096);
    }

    for (int st = 0; st < 16; ++st) {
        // Single barrier per supertile: drains vmcnt(0) (buf[st&1] loads
        // landed) and orders last tile's reads before the next issue.
        asm volatile("s_waitcnt vmcnt(0)" ::: "memory");
        __syncthreads();
        if (st < 15) {
            const float4* src = wsrc + (size_t)(st + 1) * 1024 + t;
            char* nb = ((st & 1) ? (char*)bufA : (char*)bufB) + wave * 1024;
#pragma unroll
            for (int i2 = 0; i2 < 4; ++i2)
                gload_lds16(src + i2 * 256, nb + i2 * 4096);
        }
        const bf16x8* wt = (const bf16x8*)((st & 1) ? bufB : bufA);

#pragma unroll
        for (int jj = 0; jj < 4; ++jj) {
            int j = st * 4 + jj;
            bf16x8 bh0 = wt[(jj * 4 + 0) * 64 + lane];
            bf16x8 bl0 = wt[(jj * 4 + 1) * 64 + lane];
            bf16x8 bh1 = wt[(jj * 4 + 2) * 64 + lane];
            bf16x8 bl1 = wt[(jj * 4 + 3) * 64 + lane];
            f32x4 acc0 = {0.f, 0.f, 0.f, 0.f};
            f32x4 acc1 = {0.f, 0.f, 0.f, 0.f};
            acc0 = __builtin_amdgcn_mfma_f32_16x16x32_bf16(aL[0][0], bh0, acc0, 0, 0, 0);
            acc1 = __builtin_amdgcn_mfma_f32_16x16x32_bf16(aL[1][0], bh0, acc1, 0, 0, 0);
            acc0 = __builtin_amdgcn_mfma_f32_16x16x32_bf16(aL[0][1], bh1, acc0, 0, 0, 0);
            acc1 = __builtin_amdgcn_mfma_f32_16x16x32_bf16(aL[1][1], bh1, acc1, 0, 0, 0);
            acc0 = __builtin_amdgcn_mfma_f32_16x16x32_bf16(aH[0][0], bl0, acc0, 0, 0, 0);
            acc1 = __builtin_amdgcn_mfma_f32_16x16x32_bf16(aH[1][0], bl0, acc1, 0, 0, 0);
            acc0 = __builtin_amdgcn_mfma_f32_16x16x32_bf16(aH[0][1], bl1, acc0, 0, 0, 0);
            acc1 = __builtin_amdgcn_mfma_f32_16x16x32_bf16(aH[1][1], bl1, acc1, 0, 0, 0);
            acc0 = __builtin_amdgcn_mfma_f32_16x16x32_bf16(aH[0][0], bh0, acc0, 0, 0, 0);
            acc1 = __builtin_amdgcn_mfma_f32_16x16x32_bf16(aH[1][0], bh0, acc1, 0, 0, 0);
            acc0 = __builtin_amdgcn_mfma_f32_16x16x32_bf16(aH[0][1], bh1, acc0, 0, 0, 0);
            acc1 = __builtin_amdgcn_mfma_f32_16x16x32_bf16(aH[1][1], bh1, acc1, 0, 0, 0);
            float w2c = w2s[j * 16 + col];
#pragma unroll
            for (int s2 = 0; s2 < 2; ++s2) {
#pragma unroll
                for (int r = 0; r < 4; ++r) {
                    float s = fmaf(-2.f, (s2 ? acc1 : acc0)[r], w2c);
                    // pack 6-bit j into low mantissa: pure-fmin tracking
                    float key = __int_as_float(
                        (__float_as_int(s) & ~63) | j);
                    best2[s2][r] = fminf(best2[s2][r], fmaxf(key, best[s2][r]));
                    best[s2][r]  = fminf(best[s2][r], key);
                }
            }
        }
    }

    // Unpack candidate index from key bits.
    int bk[2][4];
#pragma unroll
    for (int s2 = 0; s2 < 2; ++s2)
#pragma unroll
        for (int r = 0; r < 4; ++r)
            bk[s2][r] = ((__float_as_int(best[s2][r]) & 63) << 4) | col;

#pragma unroll
    for (int m = 1; m < 16; m <<= 1) {
#pragma unroll
        for (int s2 = 0; s2 < 2; ++s2) {
#pragma unroll
            for (int r = 0; r < 4; ++r) {
                float ob  = __shfl_xor(best[s2][r], m, 64);
                float ob2 = __shfl_xor(best2[s2][r], m, 64);
                int   obk = __shfl_xor(bk[s2][r], m, 64);
                float nb2 = fminf(fminf(best2[s2][r], ob2),
                                  fmaxf(best[s2][r], ob));
                int   nbk = ob < best[s2][r] ? obk
                            : (best[s2][r] < ob ? bk[s2][r]
                                                : min(bk[s2][r], obk));
                best[s2][r]  = fminf(best[s2][r], ob);
                best2[s2][r] = nb2;
                bk[s2][r]    = nbk;
            }
        }
    }

    if (col == 0) {
#pragma unroll
        for (int s2 = 0; s2 < 2; ++s2) {
#pragma unroll
            for (int r = 0; r < 4; ++r) {
                int row = rowbase + wave * 32 + s2 * 16 + q * 4 + r;
                idx_ws[row]    = bk[s2][r];
                out_idx_f[row] = (float)bk[s2][r];
                if (best2[s2][r] - best[s2][r] < MARGIN_BF) {
                    int pos = atomicAdd(flagcnt, 1);
                    if (pos < FLAG_CAP) flaglist[pos] = row;
                }
            }
        }
    }
}

// fp64 rescan of flagged rows (exact); patches idx/out_idx_f before hist.
__global__ __launch_bounds__(256) void refine_kernel(
    const float* __restrict__ xt, const float* __restrict__ weight,
    const double* __restrict__ w2d, int* __restrict__ idx_ws,
    float* __restrict__ out_idx_f, const int* __restrict__ flagcnt,
    const int* __restrict__ flaglist) {
    int cnt = *flagcnt;
    if (cnt > FLAG_CAP) cnt = FLAG_CAP;

    __shared__ float  sx[D_DIM];
    __shared__ double sd[256];
    __shared__ int    si[256];
    int t = threadIdx.x;

    for (int r = blockIdx.x; r < cnt; r += gridDim.x) {
        int row = flaglist[r];
        if (t < D_DIM) sx[t] = xt[(size_t)row * D_DIM + t];
        __syncthreads();

        double x2 = 0.0;
#pragma unroll
        for (int d = 0; d < D_DIM; ++d) {
            double xv = (double)sx[d];
            x2 = fma(xv, xv, x2);
        }

        double bd = 1.0e300; int bi = 0;
#pragma unroll
        for (int jj = 0; jj < 4; ++jj) {
            int k = t + jj * 256;
            const float* wk = weight + k * D_DIM;
            double dot = 0.0;
#pragma unroll
            for (int d = 0; d < D_DIM; ++d)
                dot = fma((double)wk[d], (double)sx[d], dot);
            double dist = (x2 + w2d[k]) - 2.0 * dot;
            if (dist < bd) { bd = dist; bi = k; }
        }
        sd[t] = bd; si[t] = bi;
        __syncthreads();
        for (int s = 128; s > 0; s >>= 1) {
            if (t < s) {
                double od = sd[t + s]; int oi = si[t + s];
                if (od < sd[t] || (od == sd[t] && oi < si[t])) {
                    sd[t] = od; si[t] = oi;
                }
            }
            __syncthreads();
        }
        if (t == 0 && si[0] != idx_ws[row]) {
            idx_ws[row]    = si[0];
            out_idx_f[row] = (float)si[0];
        }
        __syncthreads();
    }
}

// Counting sort, pass 1: per-block LDS histogram of 4096 rows -> histb[b][k].
__global__ __launch_bounds__(256) void hist_kernel(
    const int* __restrict__ idx_ws, int* __restrict__ histb) {
    __shared__ int h[K_CODES];
    int t = threadIdx.x, b = blockIdx.x;
    for (int i = t; i < K_CODES; i += 256) h[i] = 0;
    __syncthreads();
    const int4* idx4 = (const int4*)idx_ws + b * 1024;
#pragma unroll
    for (int i = 0; i < 4; ++i) {
        int4 c = idx4[t + i * 256];
        atomicAdd(&h[c.x], 1); atomicAdd(&h[c.y], 1);
        atomicAdd(&h[c.z], 1); atomicAdd(&h[c.w], 1);
    }
    __syncthreads();
    for (int i = t; i < K_CODES; i += 256) histb[b * K_CODES + i] = h[i];
}

// Pass 2 (1 block, 1024 thr): column prefix over block histograms + global
// exclusive prefix -> cursors (in histb) + goff. Fused Laplace/csn.
__global__ __launch_bounds__(1024) void scan_kernel(
    int* __restrict__ histb, int* __restrict__ goff,
    const float* __restrict__ ema_cs, float* __restrict__ csbuf) {
    __shared__ int pre[K_CODES];
    __shared__ float red[K_CODES];
    int k = threadIdx.x;

    int s = 0;
    for (int b = 0; b < NHB; ++b) {
        int v = histb[b * K_CODES + k];
        histb[b * K_CODES + k] = s;  // local exclusive prefix
        s += v;
    }
    int cnt = s;

    pre[k] = cnt;
    __syncthreads();
    for (int d = 1; d < K_CODES; d <<= 1) {
        int v = (k >= d) ? pre[k - d] : 0;
        __syncthreads();
        if (k >= d) pre[k] += v;
        __syncthreads();
    }
    int base = pre[k] - cnt;
    goff[k] = base;
    if (k == K_CODES - 1) goff[K_CODES] = pre[k];

    for (int b = 0; b < NHB; ++b) histb[b * K_CODES + k] += base;

    float cs = ema_cs[k] * DECAY + OMD * (float)cnt;
    red[k] = cs;
    __syncthreads();
    for (int s2 = 512; s2 > 0; s2 >>= 1) {
        if (k < s2) red[k] += red[k + s2];
        __syncthreads();
    }
    float n = red[0];
    csbuf[k] = (cs + EPS_F) / (n + (float)K_CODES * EPS_F) * n;
}

// Pass 3: scatter row ids into code-sorted order via LDS cursors.
__global__ __launch_bounds__(256) void scatter_kernel(
    const int* __restrict__ idx_ws, const int* __restrict__ histb,
    int* __restrict__ sorted) {
    __shared__ int cur[K_CODES];
    int t = threadIdx.x, b = blockIdx.x;
    for (int i = t; i < K_CODES; i += 256) cur[i] = histb[b * K_CODES + i];
    __syncthreads();
    const int4* idx4 = (const int4*)idx_ws + b * 1024;
#pragma unroll
    for (int i = 0; i < 4; ++i) {
        int4 c = idx4[t + i * 256];
        int r0 = (b * 1024 + t + i * 256) * 4;
        sorted[atomicAdd(&cur[c.x], 1)] = r0 + 0;
        sorted[atomicAdd(&cur[c.y], 1)] = r0 + 1;
        sorted[atomicAdd(&cur[c.z], 1)] = r0 + 2;
        sorted[atomicAdd(&cur[c.w], 1)] = r0 + 3;
    }
}

// Pass 4: one block per code; gather xt rows (coalesced 256B), 2 chains for
// load ILP, LDS tree. Fused EMA+normalize: writes new_w directly (emaw kernel
// removed — saves a launch + the 512KB dw round-trip).
__global__ __launch_bounds__(256) void dwred_kernel(
    const float* __restrict__ xt, const int* __restrict__ sorted,
    const int* __restrict__ goff, const float* __restrict__ ema_w,
    const float* __restrict__ csbuf, float* __restrict__ new_w) {
    __shared__ int   rows[SEG_CAP];
    __shared__ float red[256];
    int k = blockIdx.x, t = threadIdx.x;
    int base = goff[k];
    int cnt = goff[k + 1] - base;
    int cc = cnt > SEG_CAP ? SEG_CAP : cnt;

    for (int i = t; i < cc; i += 256) rows[i] = sorted[base + i];
    __syncthreads();

    int d = t & 63, sub = t >> 6;
    float a0 = 0.f, a1 = 0.f;
    int i = sub;
    for (; i + 4 < cc; i += 8) {
        a0 += xt[(size_t)rows[i] * D_DIM + d];
        a1 += xt[(size_t)rows[i + 4] * D_DIM + d];
    }
    for (; i < cc; i += 4) a0 += xt[(size_t)rows[i] * D_DIM + d];
    red[t] = a0 + a1;
    __syncthreads();
    if (t < 64) {
        float dwv = red[t] + red[t + 64] + red[t + 128] + red[t + 192];
        new_w[k * D_DIM + t] =
            (ema_w[k * D_DIM + t] * DECAY + OMD * dwv) / csbuf[k];
    }
}

// Gather updated codebook, straight-through output, commitment-loss partials.
// Last block (completion counter) finalizes the loss scalar — loss_final
// kernel removed.
__global__ __launch_bounds__(256) void out_kernel(
    const float* __restrict__ inp, const float* __restrict__ new_w,
    const int* __restrict__ idx_ws, float* __restrict__ out,
    double* __restrict__ loss_acc, int* __restrict__ done_cnt) {
    int row = blockIdx.x * 256 + threadIdx.x;
    int b  = row >> 12;
    int hw = row & (HW - 1);
    const float* xp = inp + (size_t)b * CHW + hw;
    float* op = out + 1 + (size_t)b * CHW + hw;  // out[0] is the loss scalar

    int k = idx_ws[row];
    const float* q = new_w + k * D_DIM;

    float lsum = 0.f;
#pragma unroll
    for (int d = 0; d < D_DIM; ++d) {
        float xv = xp[(size_t)d * HW];
        float qv = q[d];
        float diff = qv - xv;            // stop_gradient(quantized) - x
        lsum = fmaf(diff, diff, lsum);
        op[(size_t)d * HW] = xv + diff;  // x + (quantized - x)
    }

    __shared__ double lred[256];
    lred[threadIdx.x] = (double)lsum;
    __syncthreads();
    for (int s = 128; s > 0; s >>= 1) {
        if (threadIdx.x < s) lred[threadIdx.x] += lred[threadIdx.x + s];
        __syncthreads();
    }
    if (threadIdx.x == 0) {
        atomicAdd(loss_acc, lred[0]);
        __threadfence();  // make our loss add visible before the count add
        int old = atomicAdd(done_cnt, 1);
        if (old == (int)gridDim.x - 1) {
            // All blocks' loss adds are ordered before their count adds;
            // read via atomic RMW for device-scope coherence.
            double v = atomicAdd(loss_acc, 0.0);
            out[0] = (float)(0.25 * (v / (double)N_ELEM));
        }
    }
}

extern "C" void kernel_launch(void* const* d_in, const int* in_sizes, int n_in,
                              void* d_out, int out_size, void* d_ws, size_t ws_size,
                              hipStream_t stream) {
    const float* inp    = (const float*)d_in[0];
    const float* weight = (const float*)d_in[1];
    const float* ema_cs = (const float*)d_in[2];
    const float* ema_w  = (const float*)d_in[3];
    float* out = (float*)d_out;

    char* ws = (char*)d_ws;
    double* loss_acc = (double*)(ws + OFF_LOSS);
    int*    flagcnt  = (int*)(ws + OFF_FLAGCNT);
    int*    done_cnt = (int*)(ws + OFF_DONE);
    float*  w2f      = (float*)(ws + OFF_W2F);
    double* w2d      = (double*)(ws + OFF_W2D);
    float*  csbuf    = (float*)(ws + OFF_CS);
    int*    goff     = (int*)(ws + OFF_GOFF);
    float*  new_w    = (float*)(ws + OFF_NEWW);
    int*    idx_ws   = (int*)(ws + OFF_IDX);
    int*    histb    = (int*)(ws + OFF_HISTB);
    int*    sorted   = (int*)(ws + OFF_SORT);
    int*    flaglist = (int*)(ws + OFF_FLAGS);
    short*  wfrag    = (short*)(ws + OFF_WFRAG);

    float* xt        = out + 1;               // scratch: overwritten by out_kernel
    float* out_idx_f = out + 1 + (size_t)N_ELEM;

    hipMemsetAsync(ws, 0, ZERO_BYTES, stream);  // loss + flagcnt + done only

    prep_kernel<<<36, 256, 0, stream>>>(weight, wfrag, w2f, w2d);

    argmin_kernel<<<N_ROWS / BROWS, 256, 0, stream>>>(
        inp, wfrag, w2f, idx_ws, out_idx_f, xt, flagcnt, flaglist);

    refine_kernel<<<1024, 256, 0, stream>>>(
        xt, weight, w2d, idx_ws, out_idx_f, flagcnt, flaglist);

    hist_kernel<<<NHB, 256, 0, stream>>>(idx_ws, histb);

    scan_kernel<<<1, 1024, 0, stream>>>(histb, goff, ema_cs, csbuf);

    scatter_kernel<<<NHB, 256, 0, stream>>>(idx_ws, histb, sorted);

    dwred_kernel<<<K_CODES, 256, 0, stream>>>(xt, sorted, goff, ema_w, csbuf, new_w);

    out_kernel<<<N_ROWS / 256, 256, 0, stream>>>(inp, new_w, idx_ws, out,
                                                 loss_acc, done_cnt);
}

// Round 3
// 436.089 us; speedup vs baseline: 1.1194x; 1.1194x over previous
//
#include <hip/hip_runtime.h>

// Problem constants (B=64, C=D=64, H=W=64, K=1024)
#define K_CODES 1024
#define D_DIM   64
#define N_ROWS  262144      // B*H*W
#define HW      4096        // H*W
#define CHW     262144      // C*H*W
#define N_ELEM  16777216    // B*C*H*W
#define DECAY   0.99f
#define OMD     0.01f       // 1 - DECAY
#define EPS_F   1e-05f
// Margin = 40 sigma of split-bf16 score noise (~1e-4) + 64-ULP j-packing
// perturbation (<=0.002 for |s|<256). Near-ties under this margin go to refine.
#define MARGIN_BF 0.008f
#define FLAG_CAP 32768      // expected flags ~1-3k
#define SEG_CAP  2048       // per-code row cap (mean 256, Poisson max ~340)
#define NHB      64         // hist blocks (4096 rows each)
#define BROWS    128        // rows per argmin block (32 per wave)

typedef __attribute__((ext_vector_type(8))) short bf16x8;  // 8 bf16 = 4 VGPRs
typedef __attribute__((ext_vector_type(4))) float f32x4;

// Workspace layout (bytes); [0,64) is the only zeroed region. All 16B-aligned.
// FLAGS and WFRAG temporally overlay SORT (dead before scatter writes it).
constexpr size_t OFF_LOSS    = 0;        // 1 double
constexpr size_t OFF_FLAGCNT = 8;        // 1 int
constexpr size_t OFF_DONE    = 12;       // 1 int (out_kernel completion count)
constexpr size_t ZERO_BYTES  = 64;
constexpr size_t OFF_W2F     = 64;       // 1024 f   -> 4160
constexpr size_t OFF_W2D     = 4160;     // 1024 d   -> 12352
constexpr size_t OFF_CS     = 12352;     // 1024 f   -> 16448
constexpr size_t OFF_GOFF    = 16448;    // 1025 i   -> 20608 (padded)
constexpr size_t OFF_DW      = 20608;    // 65536 f  -> 282752 (unused, kept)
constexpr size_t OFF_NEWW    = 282752;   // 65536 f  -> 544896
constexpr size_t OFF_IDX     = 544896;   // 262144 i -> 1593472
constexpr size_t OFF_HISTB   = 1593472;  // 64x1024 i -> 1855616
constexpr size_t OFF_SORT    = 1855616;  // 262144 i -> 2904192
constexpr size_t OFF_FLAGS   = 1855616;  // 32768 i (dead after refine)
constexpr size_t OFF_WFRAG   = 1986688;  // 131072 bf16 (dead after argmin) -> 2248832

__device__ __forceinline__ short f2bf(float f) {  // RNE float->bf16
    unsigned u = __float_as_uint(f);
    u += 0x7fffu + ((u >> 16) & 1u);
    return (short)(u >> 16);
}
__device__ __forceinline__ float bf2f(short h) {
    return __uint_as_float(((unsigned)(unsigned short)h) << 16);
}

// Async global->LDS, 16B per lane. LDS dest is wave-uniform base + lane*16
// (hardware semantics); our dest layout is linear in thread id so this holds.
__device__ __forceinline__ void gload_lds16(const float4* g, void* l) {
    __builtin_amdgcn_global_load_lds(
        (const __attribute__((address_space(1))) void*)g,
        (__attribute__((address_space(3))) void*)l, 16, 0, 0);
}

// One-time prep: W swizzled to bf16 hi/lo B-fragment pairs for 16x16x32 MFMA.
__global__ __launch_bounds__(256) void prep_kernel(
    const float* __restrict__ w, short* __restrict__ wfrag,
    float* __restrict__ w2f, double* __restrict__ w2d) {
    int t = threadIdx.x;
    if (blockIdx.x < 32) {
        int gid = blockIdx.x * 256 + t;  // (j<<7)|(h<<6)|L
        int j = gid >> 7, h = (gid >> 6) & 1, L = gid & 63;
        int code = j * 16 + (L & 15);
        int kb = h * 32 + ((L >> 4) << 3);
        const float* wp = w + code * D_DIM + kb;
        short hi[8], lo[8];
#pragma unroll
        for (int i = 0; i < 8; ++i) {
            float v = wp[i];
            short hb = f2bf(v);
            hi[i] = hb;
            lo[i] = f2bf(v - bf2f(hb));
        }
        short* dh = wfrag + (size_t)(((j * 2 + h) * 2 + 0) * 64 + L) * 8;
        short* dl = wfrag + (size_t)(((j * 2 + h) * 2 + 1) * 64 + L) * 8;
#pragma unroll
        for (int i = 0; i < 8; ++i) { dh[i] = hi[i]; dl[i] = lo[i]; }
    } else {
        int k = (blockIdx.x - 32) * 256 + t;
        const float* wk = w + k * D_DIM;
        float sf = 0.f; double sd = 0.0;
#pragma unroll
        for (int d = 0; d < D_DIM; ++d) {
            float wv = wk[d];
            sf = fmaf(wv, wv, sf);
            sd = fma((double)wv, (double)wv, sd);
        }
        w2f[k] = sf; w2d[k] = sd;
    }
}

// Split-bf16 MFMA argmin. R9: 32 rows/wave (halved per-row LDS B-fragment
// traffic vs 16 rows/wave) AND 4 blocks/CU: x is staged in TWO 64-row passes
// through a 17.4KB xs buffer (R8's single-pass 128-row xs cost 55KB LDS ->
// 2 blocks/CU -> occupancy 20% -> net wash). LDS = 4K(w2s) + 17408(xs union
// bufB) + 16K(bufA) = 37888B -> 4 blocks/CU = 16 waves/CU.
// Min-tracking packs the 6-bit supertile index j into the low mantissa bits
// of the score (pure fmin/med3 tracking, no cmp/cndmask); the <=64-ULP
// perturbation is covered by MARGIN_BF + fp64 refine.
__global__ __launch_bounds__(256) __attribute__((amdgpu_waves_per_eu(2, 4)))
void argmin_kernel(
    const float* __restrict__ inp, const short* __restrict__ wfrag,
    const float* __restrict__ w2f, int* __restrict__ idx_ws,
    float* __restrict__ out_idx_f, float* __restrict__ xt,
    int* __restrict__ flagcnt, int* __restrict__ flaglist) {
    __shared__ float w2s[K_CODES];
    __shared__ alignas(16) char smem_u[64 * 68 * 4];  // xs(17408B) / bufB(16KB) union
    __shared__ alignas(16) short bufA[8192];          // 16 KB
    float (*xs)[68] = (float (*)[68])smem_u;          // +4 pad per row
    short* bufB = (short*)smem_u;

    int t = threadIdx.x;
    ((float4*)w2s)[t] = ((const float4*)w2f)[t];

    int rowbase = blockIdx.x * BROWS;
    int b = rowbase >> 12, hwb = rowbase & (HW - 1);
    const float* xp = inp + (size_t)b * CHW + hwb;
    int lane = t & 63, wave = t >> 6;
    int q = lane >> 4, col = lane & 15;

    bf16x8 aH[2][2], aL[2][2];  // [row-set][k-half]; built in owning pass

    // Two staging passes: pass p covers block rows p*64..p*64+63.
    for (int p = 0; p < 2; ++p) {
#pragma unroll
        for (int it = 0; it < 16; ++it) {
            int d = wave * 16 + it;
            xs[lane][d] = xp[(size_t)d * HW + p * 64 + lane];  // coalesced 256B
        }
        __syncthreads();

        // xt side-product: coalesced row-major dump of these 64 rows
        float4* xt4 = (float4*)(xt + (size_t)(rowbase + p * 64) * D_DIM);
#pragma unroll
        for (int i2 = 0; i2 < 4; ++i2) {
            int c2 = t + i2 * 256;
            xt4[c2] = ((const float4*)xs[c2 >> 4])[c2 & 15];
        }

        // Waves 2p, 2p+1 own these 64 rows: build their A-fragments.
        if ((wave >> 1) == p) {
#pragma unroll
            for (int s2 = 0; s2 < 2; ++s2) {
                int rl = (wave & 1) * 32 + s2 * 16 + col;
#pragma unroll
                for (int h = 0; h < 2; ++h) {
#pragma unroll
                    for (int i = 0; i < 8; ++i) {
                        float v = xs[rl][h * 32 + q * 8 + i];
                        short hb = f2bf(v);
                        aH[s2][h][i] = hb;
                        aL[s2][h][i] = f2bf(v - bf2f(hb));
                    }
                }
            }
        }
        __syncthreads();  // all xs reads done before overwrite / bufB use
    }

    float best[2][4], best2[2][4];
#pragma unroll
    for (int s2 = 0; s2 < 2; ++s2)
#pragma unroll
        for (int r = 0; r < 4; ++r) { best[s2][r] = 3.4e38f; best2[s2][r] = 3.4e38f; }
    const float4* wsrc = (const float4*)wfrag;

    // Prologue: issue supertile 0 into bufA. bufB (xs alias) is first written
    // at st=0 AFTER the loop-top barrier.
    {
        const float4* src = wsrc + t;
        char* nb = (char*)bufA + wave * 1024;
#pragma unroll
        for (int i2 = 0; i2 < 4; ++i2)
            gload_lds16(src + i2 * 256, nb + i2 * 4096);
    }

    for (int st = 0; st < 16; ++st) {
        // Single barrier per supertile: drains vmcnt(0) (buf[st&1] loads
        // landed) and orders last tile's reads before the next issue.
        asm volatile("s_waitcnt vmcnt(0)" ::: "memory");
        __syncthreads();
        if (st < 15) {
            const float4* src = wsrc + (size_t)(st + 1) * 1024 + t;
            char* nb = ((st & 1) ? (char*)bufA : (char*)bufB) + wave * 1024;
#pragma unroll
            for (int i2 = 0; i2 < 4; ++i2)
                gload_lds16(src + i2 * 256, nb + i2 * 4096);
        }
        const bf16x8* wt = (const bf16x8*)((st & 1) ? bufB : bufA);

#pragma unroll
        for (int jj = 0; jj < 4; ++jj) {
            int j = st * 4 + jj;
            bf16x8 bh0 = wt[(jj * 4 + 0) * 64 + lane];
            bf16x8 bl0 = wt[(jj * 4 + 1) * 64 + lane];
            bf16x8 bh1 = wt[(jj * 4 + 2) * 64 + lane];
            bf16x8 bl1 = wt[(jj * 4 + 3) * 64 + lane];
            f32x4 acc0 = {0.f, 0.f, 0.f, 0.f};
            f32x4 acc1 = {0.f, 0.f, 0.f, 0.f};
            acc0 = __builtin_amdgcn_mfma_f32_16x16x32_bf16(aL[0][0], bh0, acc0, 0, 0, 0);
            acc1 = __builtin_amdgcn_mfma_f32_16x16x32_bf16(aL[1][0], bh0, acc1, 0, 0, 0);
            acc0 = __builtin_amdgcn_mfma_f32_16x16x32_bf16(aL[0][1], bh1, acc0, 0, 0, 0);
            acc1 = __builtin_amdgcn_mfma_f32_16x16x32_bf16(aL[1][1], bh1, acc1, 0, 0, 0);
            acc0 = __builtin_amdgcn_mfma_f32_16x16x32_bf16(aH[0][0], bl0, acc0, 0, 0, 0);
            acc1 = __builtin_amdgcn_mfma_f32_16x16x32_bf16(aH[1][0], bl0, acc1, 0, 0, 0);
            acc0 = __builtin_amdgcn_mfma_f32_16x16x32_bf16(aH[0][1], bl1, acc0, 0, 0, 0);
            acc1 = __builtin_amdgcn_mfma_f32_16x16x32_bf16(aH[1][1], bl1, acc1, 0, 0, 0);
            acc0 = __builtin_amdgcn_mfma_f32_16x16x32_bf16(aH[0][0], bh0, acc0, 0, 0, 0);
            acc1 = __builtin_amdgcn_mfma_f32_16x16x32_bf16(aH[1][0], bh0, acc1, 0, 0, 0);
            acc0 = __builtin_amdgcn_mfma_f32_16x16x32_bf16(aH[0][1], bh1, acc0, 0, 0, 0);
            acc1 = __builtin_amdgcn_mfma_f32_16x16x32_bf16(aH[1][1], bh1, acc1, 0, 0, 0);
            float w2c = w2s[j * 16 + col];
#pragma unroll
            for (int s2 = 0; s2 < 2; ++s2) {
#pragma unroll
                for (int r = 0; r < 4; ++r) {
                    float s = fmaf(-2.f, (s2 ? acc1 : acc0)[r], w2c);
                    // pack 6-bit j into low mantissa: pure-fmin tracking
                    float key = __int_as_float(
                        (__float_as_int(s) & ~63) | j);
                    // runner-up via median (med3 idiom; best<=best2 invariant)
                    best2[s2][r] = fminf(best2[s2][r], fmaxf(key, best[s2][r]));
                    best[s2][r]  = fminf(best[s2][r], key);
                }
            }
        }
    }

    // Unpack candidate index from key bits.
    int bk[2][4];
#pragma unroll
    for (int s2 = 0; s2 < 2; ++s2)
#pragma unroll
        for (int r = 0; r < 4; ++r)
            bk[s2][r] = ((__float_as_int(best[s2][r]) & 63) << 4) | col;

#pragma unroll
    for (int m = 1; m < 16; m <<= 1) {
#pragma unroll
        for (int s2 = 0; s2 < 2; ++s2) {
#pragma unroll
            for (int r = 0; r < 4; ++r) {
                float ob  = __shfl_xor(best[s2][r], m, 64);
                float ob2 = __shfl_xor(best2[s2][r], m, 64);
                int   obk = __shfl_xor(bk[s2][r], m, 64);
                float nb2 = fminf(fminf(best2[s2][r], ob2),
                                  fmaxf(best[s2][r], ob));
                int   nbk = ob < best[s2][r] ? obk
                            : (best[s2][r] < ob ? bk[s2][r]
                                                : min(bk[s2][r], obk));
                best[s2][r]  = fminf(best[s2][r], ob);
                best2[s2][r] = nb2;
                bk[s2][r]    = nbk;
            }
        }
    }

    if (col == 0) {
#pragma unroll
        for (int s2 = 0; s2 < 2; ++s2) {
#pragma unroll
            for (int r = 0; r < 4; ++r) {
                int row = rowbase + wave * 32 + s2 * 16 + q * 4 + r;
                idx_ws[row]    = bk[s2][r];
                out_idx_f[row] = (float)bk[s2][r];
                if (best2[s2][r] - best[s2][r] < MARGIN_BF) {
                    int pos = atomicAdd(flagcnt, 1);
                    if (pos < FLAG_CAP) flaglist[pos] = row;
                }
            }
        }
    }
}

// fp64 rescan of flagged rows (exact); patches idx/out_idx_f before hist.
// R9 rewrite: wave-per-row (was block-per-row with ~16 syncthreads and a
// 256-KB codebook sweep per block). Lane owns 16 contiguous codes; f64 dots
// via float4 weight loads; 6-step shfl min with lowest-index tiebreak.
// x^2 dropped (constant per row — ordering-invariant).
__global__ __launch_bounds__(256) void refine_kernel(
    const float* __restrict__ xt, const float* __restrict__ weight,
    const double* __restrict__ w2d, int* __restrict__ idx_ws,
    float* __restrict__ out_idx_f, const int* __restrict__ flagcnt,
    const int* __restrict__ flaglist) {
    __shared__ float sx[4][64];
    int cnt = *flagcnt;
    if (cnt > FLAG_CAP) cnt = FLAG_CAP;
    int t = threadIdx.x, lane = t & 63, wave = t >> 6;

    for (int r = blockIdx.x * 4 + wave; r < cnt; r += gridDim.x * 4) {
        int row = flaglist[r];
        sx[wave][lane] = xt[(size_t)row * D_DIM + lane];
        // same-wave DS write->read ordering; drain lgkm before the dot loop
        asm volatile("s_waitcnt lgkmcnt(0)" ::: "memory");

        double bd = 1.0e300; int bi = 0;
        int k0 = lane * 16;
#pragma unroll 4
        for (int c = 0; c < 16; ++c) {
            int k = k0 + c;
            const float4* wk4 = (const float4*)(weight + (size_t)k * D_DIM);
            double dot = 0.0;
#pragma unroll
            for (int d4 = 0; d4 < 16; ++d4) {
                float4 wv = wk4[d4];
                dot = fma((double)wv.x, (double)sx[wave][d4 * 4 + 0], dot);
                dot = fma((double)wv.y, (double)sx[wave][d4 * 4 + 1], dot);
                dot = fma((double)wv.z, (double)sx[wave][d4 * 4 + 2], dot);
                dot = fma((double)wv.w, (double)sx[wave][d4 * 4 + 3], dot);
            }
            double dist = w2d[k] - 2.0 * dot;  // x^2 omitted (constant)
            if (dist < bd) { bd = dist; bi = k; }
        }
#pragma unroll
        for (int m = 1; m < 64; m <<= 1) {
            double od = __shfl_xor(bd, m, 64);
            int    oi = __shfl_xor(bi, m, 64);
            if (od < bd || (od == bd && oi < bi)) { bd = od; bi = oi; }
        }
        if (lane == 0 && bi != idx_ws[row]) {
            idx_ws[row]    = bi;
            out_idx_f[row] = (float)bi;
        }
    }
}

// Counting sort, pass 1: per-block LDS histogram of 4096 rows -> histb[b][k].
__global__ __launch_bounds__(256) void hist_kernel(
    const int* __restrict__ idx_ws, int* __restrict__ histb) {
    __shared__ int h[K_CODES];
    int t = threadIdx.x, b = blockIdx.x;
    for (int i = t; i < K_CODES; i += 256) h[i] = 0;
    __syncthreads();
    const int4* idx4 = (const int4*)idx_ws + b * 1024;
#pragma unroll
    for (int i = 0; i < 4; ++i) {
        int4 c = idx4[t + i * 256];
        atomicAdd(&h[c.x], 1); atomicAdd(&h[c.y], 1);
        atomicAdd(&h[c.z], 1); atomicAdd(&h[c.w], 1);
    }
    __syncthreads();
    for (int i = t; i < K_CODES; i += 256) histb[b * K_CODES + i] = h[i];
}

// Pass 2 (1 block, 1024 thr): column prefix over block histograms + global
// exclusive prefix -> cursors (in histb) + goff. Fused Laplace/csn.
__global__ __launch_bounds__(1024) void scan_kernel(
    int* __restrict__ histb, int* __restrict__ goff,
    const float* __restrict__ ema_cs, float* __restrict__ csbuf) {
    __shared__ int pre[K_CODES];
    __shared__ float red[K_CODES];
    int k = threadIdx.x;

    int s = 0;
    for (int b = 0; b < NHB; ++b) {
        int v = histb[b * K_CODES + k];
        histb[b * K_CODES + k] = s;  // local exclusive prefix
        s += v;
    }
    int cnt = s;

    pre[k] = cnt;
    __syncthreads();
    for (int d = 1; d < K_CODES; d <<= 1) {
        int v = (k >= d) ? pre[k - d] : 0;
        __syncthreads();
        if (k >= d) pre[k] += v;
        __syncthreads();
    }
    int base = pre[k] - cnt;
    goff[k] = base;
    if (k == K_CODES - 1) goff[K_CODES] = pre[k];

    for (int b = 0; b < NHB; ++b) histb[b * K_CODES + k] += base;

    float cs = ema_cs[k] * DECAY + OMD * (float)cnt;
    red[k] = cs;
    __syncthreads();
    for (int s2 = 512; s2 > 0; s2 >>= 1) {
        if (k < s2) red[k] += red[k + s2];
        __syncthreads();
    }
    float n = red[0];
    csbuf[k] = (cs + EPS_F) / (n + (float)K_CODES * EPS_F) * n;
}

// Pass 3: scatter row ids into code-sorted order via LDS cursors.
__global__ __launch_bounds__(256) void scatter_kernel(
    const int* __restrict__ idx_ws, const int* __restrict__ histb,
    int* __restrict__ sorted) {
    __shared__ int cur[K_CODES];
    int t = threadIdx.x, b = blockIdx.x;
    for (int i = t; i < K_CODES; i += 256) cur[i] = histb[b * K_CODES + i];
    __syncthreads();
    const int4* idx4 = (const int4*)idx_ws + b * 1024;
#pragma unroll
    for (int i = 0; i < 4; ++i) {
        int4 c = idx4[t + i * 256];
        int r0 = (b * 1024 + t + i * 256) * 4;
        sorted[atomicAdd(&cur[c.x], 1)] = r0 + 0;
        sorted[atomicAdd(&cur[c.y], 1)] = r0 + 1;
        sorted[atomicAdd(&cur[c.z], 1)] = r0 + 2;
        sorted[atomicAdd(&cur[c.w], 1)] = r0 + 3;
    }
}

// Pass 4: one block per code; gather xt rows (coalesced 256B), 2 chains for
// load ILP, LDS tree. Fused EMA+normalize: writes new_w directly.
__global__ __launch_bounds__(256) void dwred_kernel(
    const float* __restrict__ xt, const int* __restrict__ sorted,
    const int* __restrict__ goff, const float* __restrict__ ema_w,
    const float* __restrict__ csbuf, float* __restrict__ new_w) {
    __shared__ int   rows[SEG_CAP];
    __shared__ float red[256];
    int k = blockIdx.x, t = threadIdx.x;
    int base = goff[k];
    int cnt = goff[k + 1] - base;
    int cc = cnt > SEG_CAP ? SEG_CAP : cnt;

    for (int i = t; i < cc; i += 256) rows[i] = sorted[base + i];
    __syncthreads();

    int d = t & 63, sub = t >> 6;
    float a0 = 0.f, a1 = 0.f;
    int i = sub;
    for (; i + 4 < cc; i += 8) {
        a0 += xt[(size_t)rows[i] * D_DIM + d];
        a1 += xt[(size_t)rows[i + 4] * D_DIM + d];
    }
    for (; i < cc; i += 4) a0 += xt[(size_t)rows[i] * D_DIM + d];
    red[t] = a0 + a1;
    __syncthreads();
    if (t < 64) {
        float dwv = red[t] + red[t + 64] + red[t + 128] + red[t + 192];
        new_w[k * D_DIM + t] =
            (ema_w[k * D_DIM + t] * DECAY + OMD * dwv) / csbuf[k];
    }
}

// Gather updated codebook, straight-through output, commitment-loss partials.
// Last block (completion counter) finalizes the loss scalar.
__global__ __launch_bounds__(256) void out_kernel(
    const float* __restrict__ inp, const float* __restrict__ new_w,
    const int* __restrict__ idx_ws, float* __restrict__ out,
    double* __restrict__ loss_acc, int* __restrict__ done_cnt) {
    int row = blockIdx.x * 256 + threadIdx.x;
    int b  = row >> 12;
    int hw = row & (HW - 1);
    const float* xp = inp + (size_t)b * CHW + hw;
    float* op = out + 1 + (size_t)b * CHW + hw;  // out[0] is the loss scalar

    int k = idx_ws[row];
    const float* q = new_w + k * D_DIM;

    float lsum = 0.f;
#pragma unroll
    for (int d = 0; d < D_DIM; ++d) {
        float xv = xp[(size_t)d * HW];
        float qv = q[d];
        float diff = qv - xv;            // stop_gradient(quantized) - x
        lsum = fmaf(diff, diff, lsum);
        op[(size_t)d * HW] = xv + diff;  // x + (quantized - x)
    }

    __shared__ double lred[256];
    lred[threadIdx.x] = (double)lsum;
    __syncthreads();
    for (int s = 128; s > 0; s >>= 1) {
        if (threadIdx.x < s) lred[threadIdx.x] += lred[threadIdx.x + s];
        __syncthreads();
    }
    if (threadIdx.x == 0) {
        atomicAdd(loss_acc, lred[0]);
        __threadfence();  // make our loss add visible before the count add
        int old = atomicAdd(done_cnt, 1);
        if (old == (int)gridDim.x - 1) {
            double v = atomicAdd(loss_acc, 0.0);
            out[0] = (float)(0.25 * (v / (double)N_ELEM));
        }
    }
}

extern "C" void kernel_launch(void* const* d_in, const int* in_sizes, int n_in,
                              void* d_out, int out_size, void* d_ws, size_t ws_size,
                              hipStream_t stream) {
    const float* inp    = (const float*)d_in[0];
    const float* weight = (const float*)d_in[1];
    const float* ema_cs = (const float*)d_in[2];
    const float* ema_w  = (const float*)d_in[3];
    float* out = (float*)d_out;

    char* ws = (char*)d_ws;
    double* loss_acc = (double*)(ws + OFF_LOSS);
    int*    flagcnt  = (int*)(ws + OFF_FLAGCNT);
    int*    done_cnt = (int*)(ws + OFF_DONE);
    float*  w2f      = (float*)(ws + OFF_W2F);
    double* w2d      = (double*)(ws + OFF_W2D);
    float*  csbuf    = (float*)(ws + OFF_CS);
    int*    goff     = (int*)(ws + OFF_GOFF);
    float*  new_w    = (float*)(ws + OFF_NEWW);
    int*    idx_ws   = (int*)(ws + OFF_IDX);
    int*    histb    = (int*)(ws + OFF_HISTB);
    int*    sorted   = (int*)(ws + OFF_SORT);
    int*    flaglist = (int*)(ws + OFF_FLAGS);
    short*  wfrag    = (short*)(ws + OFF_WFRAG);

    float* xt        = out + 1;               // scratch: overwritten by out_kernel
    float* out_idx_f = out + 1 + (size_t)N_ELEM;

    hipMemsetAsync(ws, 0, ZERO_BYTES, stream);  // loss + flagcnt + done only

    prep_kernel<<<36, 256, 0, stream>>>(weight, wfrag, w2f, w2d);

    argmin_kernel<<<N_ROWS / BROWS, 256, 0, stream>>>(
        inp, wfrag, w2f, idx_ws, out_idx_f, xt, flagcnt, flaglist);

    refine_kernel<<<256, 256, 0, stream>>>(
        xt, weight, w2d, idx_ws, out_idx_f, flagcnt, flaglist);

    hist_kernel<<<NHB, 256, 0, stream>>>(idx_ws, histb);

    scan_kernel<<<1, 1024, 0, stream>>>(histb, goff, ema_cs, csbuf);

    scatter_kernel<<<NHB, 256, 0, stream>>>(idx_ws, histb, sorted);

    dwred_kernel<<<K_CODES, 256, 0, stream>>>(xt, sorted, goff, ema_w, csbuf, new_w);

    out_kernel<<<N_ROWS / 256, 256, 0, stream>>>(inp, new_w, idx_ws, out,
                                                 loss_acc, done_cnt);
}

// Round 4
// 434.102 us; speedup vs baseline: 1.1245x; 1.0046x over previous
//
#include <hip/hip_runtime.h>

// Problem constants (B=64, C=D=64, H=W=64, K=1024)
#define K_CODES 1024
#define D_DIM   64
#define N_ROWS  262144      // B*H*W
#define HW      4096        // H*W
#define CHW     262144      // C*H*W
#define N_ELEM  16777216    // B*C*H*W
#define DECAY   0.99f
#define OMD     0.01f       // 1 - DECAY
#define EPS_F   1e-05f
// Max-domain margin (acc units: m = dot - w^2/2; dist-gap = 2*acc-gap).
// Dist margin 0.008 = split-bf16 worst-case (64 * max|xl*wl| ~ 6e-3) +
// j-packing 64-ULP perturbation (~2e-3). Acc margin = half that.
#define MARGIN_ACC 0.004f
#define FLAG_CAP 32768      // expected flags ~1-6k
#define SEG_CAP  2048       // per-code row cap (mean 256, Poisson max ~340)
#define NHB      64         // hist blocks (4096 rows each)
#define BROWS    128        // rows per argmin block (32 per wave)

typedef __attribute__((ext_vector_type(8))) short bf16x8;  // 8 bf16 = 4 VGPRs
typedef __attribute__((ext_vector_type(4))) float f32x4;

// Workspace layout (bytes); [0,64) is the only zeroed region. All 16B-aligned.
// FLAGS and WFRAG temporally overlay SORT (dead before scatter writes it).
constexpr size_t OFF_LOSS    = 0;        // 1 double
constexpr size_t OFF_FLAGCNT = 8;        // 1 int
constexpr size_t OFF_DONE    = 12;       // 1 int (out_kernel completion count)
constexpr size_t OFF_W2F     = 64;       // 1024 f   -> 4160
constexpr size_t OFF_W2D     = 4160;     // 1024 d   -> 12352
constexpr size_t OFF_CS     = 12352;     // 1024 f   -> 16448
constexpr size_t OFF_GOFF    = 16448;    // 1025 i   -> 20608 (padded)
constexpr size_t OFF_NEWW    = 282752;   // 65536 f  -> 544896
constexpr size_t OFF_IDX     = 544896;   // 262144 i -> 1593472
constexpr size_t OFF_HISTB   = 1593472;  // 64x1024 i -> 1855616
constexpr size_t OFF_SORT    = 1855616;  // 262144 i -> 2904192
constexpr size_t OFF_FLAGS   = 1855616;  // 32768 i (dead after refine)
constexpr size_t OFF_WFRAG   = 1986688;  // 131072 bf16 (dead after argmin) -> 2248832

__device__ __forceinline__ short f2bf(float f) {  // RNE float->bf16
    unsigned u = __float_as_uint(f);
    u += 0x7fffu + ((u >> 16) & 1u);
    return (short)(u >> 16);
}
__device__ __forceinline__ float bf2f(short h) {
    return __uint_as_float(((unsigned)(unsigned short)h) << 16);
}

// Async global->LDS, 16B per lane. LDS dest is wave-uniform base + lane*16
// (hardware semantics); our dest layout is linear in thread id so this holds.
__device__ __forceinline__ void gload_lds16(const float4* g, void* l) {
    __builtin_amdgcn_global_load_lds(
        (const __attribute__((address_space(1))) void*)g,
        (__attribute__((address_space(3))) void*)l, 16, 0, 0);
}

// One-time prep: W swizzled to bf16 hi/lo B-fragment pairs for 16x16x32 MFMA.
// Block 35 thread 0..3 also zeroes the loss/flagcnt/done scalars (replaces
// the hipMemsetAsync enqueue; prep is stream-ordered before all consumers).
__global__ __launch_bounds__(256) void prep_kernel(
    const float* __restrict__ w, short* __restrict__ wfrag,
    float* __restrict__ w2f, double* __restrict__ w2d,
    int* __restrict__ zero16) {
    int t = threadIdx.x;
    if (blockIdx.x == 35 && t < 4) zero16[t] = 0;
    if (blockIdx.x < 32) {
        int gid = blockIdx.x * 256 + t;  // (j<<7)|(h<<6)|L
        int j = gid >> 7, h = (gid >> 6) & 1, L = gid & 63;
        int code = j * 16 + (L & 15);
        int kb = h * 32 + ((L >> 4) << 3);
        const float* wp = w + code * D_DIM + kb;
        short hi[8], lo[8];
#pragma unroll
        for (int i = 0; i < 8; ++i) {
            float v = wp[i];
            short hb = f2bf(v);
            hi[i] = hb;
            lo[i] = f2bf(v - bf2f(hb));
        }
        short* dh = wfrag + (size_t)(((j * 2 + h) * 2 + 0) * 64 + L) * 8;
        short* dl = wfrag + (size_t)(((j * 2 + h) * 2 + 1) * 64 + L) * 8;
#pragma unroll
        for (int i = 0; i < 8; ++i) { dh[i] = hi[i]; dl[i] = lo[i]; }
    } else {
        int k = (blockIdx.x - 32) * 256 + t;
        const float* wk = w + k * D_DIM;
        float sf = 0.f; double sd = 0.0;
#pragma unroll
        for (int d = 0; d < D_DIM; ++d) {
            float wv = wk[d];
            sf = fmaf(wv, wv, sf);
            sd = fma((double)wv, (double)wv, sd);
        }
        w2f[k] = sf; w2d[k] = sd;
    }
}

// Split-bf16 MFMA argmin, 32 rows/wave, 4 blocks/CU.
// R10 (VALU cut; R3 showed VALUBusy/MfmaUtil = 58/35 ~= the static op ratio
// of the scoreboard update -> issue-bound on VALU):
//  (a) max-domain accumulator init: acc = -0.5*w2(c), so acc_final =
//      dot - w2/2 and argmin(dist) = argmax(acc). Deletes the per-score
//      fmaf(-2,acc,w2c) AND the per-jj zero-init.
//  (b) jj processed in PAIRS with exact pairwise (max, 2nd-max) update:
//      5 ops per 2 scores instead of 2x5 (max3-fusable nesting).
// Together: ~224 -> ~148 VALU per supertile in the scoreboard path.
__global__ __launch_bounds__(256) __attribute__((amdgpu_waves_per_eu(2, 4)))
void argmin_kernel(
    const float* __restrict__ inp, const short* __restrict__ wfrag,
    const float* __restrict__ w2f, int* __restrict__ idx_ws,
    float* __restrict__ out_idx_f, float* __restrict__ xt,
    int* __restrict__ flagcnt, int* __restrict__ flaglist) {
    __shared__ float w2s[K_CODES];
    __shared__ alignas(16) char smem_u[64 * 68 * 4];  // xs(17408B) / bufB(16KB) union
    __shared__ alignas(16) short bufA[8192];          // 16 KB
    float (*xs)[68] = (float (*)[68])smem_u;          // +4 pad per row
    short* bufB = (short*)smem_u;

    int t = threadIdx.x;
    ((float4*)w2s)[t] = ((const float4*)w2f)[t];

    int rowbase = blockIdx.x * BROWS;
    int b = rowbase >> 12, hwb = rowbase & (HW - 1);
    const float* xp = inp + (size_t)b * CHW + hwb;
    int lane = t & 63, wave = t >> 6;
    int q = lane >> 4, col = lane & 15;

    bf16x8 aH[2][2], aL[2][2];  // [row-set][k-half]; built in owning pass

    // Two staging passes: pass p covers block rows p*64..p*64+63.
    for (int p = 0; p < 2; ++p) {
#pragma unroll
        for (int it = 0; it < 16; ++it) {
            int d = wave * 16 + it;
            xs[lane][d] = xp[(size_t)d * HW + p * 64 + lane];  // coalesced 256B
        }
        __syncthreads();

        // xt side-product: coalesced row-major dump of these 64 rows
        float4* xt4 = (float4*)(xt + (size_t)(rowbase + p * 64) * D_DIM);
#pragma unroll
        for (int i2 = 0; i2 < 4; ++i2) {
            int c2 = t + i2 * 256;
            xt4[c2] = ((const float4*)xs[c2 >> 4])[c2 & 15];
        }

        // Waves 2p, 2p+1 own these 64 rows: build their A-fragments.
        if ((wave >> 1) == p) {
#pragma unroll
            for (int s2 = 0; s2 < 2; ++s2) {
                int rl = (wave & 1) * 32 + s2 * 16 + col;
#pragma unroll
                for (int h = 0; h < 2; ++h) {
#pragma unroll
                    for (int i = 0; i < 8; ++i) {
                        float v = xs[rl][h * 32 + q * 8 + i];
                        short hb = f2bf(v);
                        aH[s2][h][i] = hb;
                        aL[s2][h][i] = f2bf(v - bf2f(hb));
                    }
                }
            }
        }
        __syncthreads();  // all xs reads done before overwrite / bufB use
    }

    // Max-domain tracking: best = largest acc (smallest dist), best2 = 2nd.
    float best[2][4], best2[2][4];
#pragma unroll
    for (int s2 = 0; s2 < 2; ++s2)
#pragma unroll
        for (int r = 0; r < 4; ++r) { best[s2][r] = -3.4e38f; best2[s2][r] = -3.4e38f; }
    const float4* wsrc = (const float4*)wfrag;

    // Prologue: issue supertile 0 into bufA. bufB (xs alias) is first written
    // at st=0 AFTER the loop-top barrier.
    {
        const float4* src = wsrc + t;
        char* nb = (char*)bufA + wave * 1024;
#pragma unroll
        for (int i2 = 0; i2 < 4; ++i2)
            gload_lds16(src + i2 * 256, nb + i2 * 4096);
    }

    for (int st = 0; st < 16; ++st) {
        // Single barrier per supertile: drains vmcnt(0) (buf[st&1] loads
        // landed) and orders last tile's reads before the next issue.
        asm volatile("s_waitcnt vmcnt(0)" ::: "memory");
        __syncthreads();
        if (st < 15) {
            const float4* src = wsrc + (size_t)(st + 1) * 1024 + t;
            char* nb = ((st & 1) ? (char*)bufA : (char*)bufB) + wave * 1024;
#pragma unroll
            for (int i2 = 0; i2 < 4; ++i2)
                gload_lds16(src + i2 * 256, nb + i2 * 4096);
        }
        const bf16x8* wt = (const bf16x8*)((st & 1) ? bufB : bufA);

#pragma unroll
        for (int jp = 0; jp < 2; ++jp) {
            int jA = st * 4 + jp * 2, jB = jA + 1;
            int jjA = jp * 2, jjB = jp * 2 + 1;
            bf16x8 bh0A = wt[(jjA * 4 + 0) * 64 + lane];
            bf16x8 bl0A = wt[(jjA * 4 + 1) * 64 + lane];
            bf16x8 bh1A = wt[(jjA * 4 + 2) * 64 + lane];
            bf16x8 bl1A = wt[(jjA * 4 + 3) * 64 + lane];
            bf16x8 bh0B = wt[(jjB * 4 + 0) * 64 + lane];
            bf16x8 bl0B = wt[(jjB * 4 + 1) * 64 + lane];
            bf16x8 bh1B = wt[(jjB * 4 + 2) * 64 + lane];
            bf16x8 bl1B = wt[(jjB * 4 + 3) * 64 + lane];
            float cA = -0.5f * w2s[jA * 16 + col];
            float cB = -0.5f * w2s[jB * 16 + col];
            f32x4 a0A = {cA, cA, cA, cA}, a1A = {cA, cA, cA, cA};
            f32x4 a0B = {cB, cB, cB, cB}, a1B = {cB, cB, cB, cB};
            a0A = __builtin_amdgcn_mfma_f32_16x16x32_bf16(aL[0][0], bh0A, a0A, 0, 0, 0);
            a1A = __builtin_amdgcn_mfma_f32_16x16x32_bf16(aL[1][0], bh0A, a1A, 0, 0, 0);
            a0B = __builtin_amdgcn_mfma_f32_16x16x32_bf16(aL[0][0], bh0B, a0B, 0, 0, 0);
            a1B = __builtin_amdgcn_mfma_f32_16x16x32_bf16(aL[1][0], bh0B, a1B, 0, 0, 0);
            a0A = __builtin_amdgcn_mfma_f32_16x16x32_bf16(aL[0][1], bh1A, a0A, 0, 0, 0);
            a1A = __builtin_amdgcn_mfma_f32_16x16x32_bf16(aL[1][1], bh1A, a1A, 0, 0, 0);
            a0B = __builtin_amdgcn_mfma_f32_16x16x32_bf16(aL[0][1], bh1B, a0B, 0, 0, 0);
            a1B = __builtin_amdgcn_mfma_f32_16x16x32_bf16(aL[1][1], bh1B, a1B, 0, 0, 0);
            a0A = __builtin_amdgcn_mfma_f32_16x16x32_bf16(aH[0][0], bl0A, a0A, 0, 0, 0);
            a1A = __builtin_amdgcn_mfma_f32_16x16x32_bf16(aH[1][0], bl0A, a1A, 0, 0, 0);
            a0B = __builtin_amdgcn_mfma_f32_16x16x32_bf16(aH[0][0], bl0B, a0B, 0, 0, 0);
            a1B = __builtin_amdgcn_mfma_f32_16x16x32_bf16(aH[1][0], bl0B, a1B, 0, 0, 0);
            a0A = __builtin_amdgcn_mfma_f32_16x16x32_bf16(aH[0][1], bl1A, a0A, 0, 0, 0);
            a1A = __builtin_amdgcn_mfma_f32_16x16x32_bf16(aH[1][1], bl1A, a1A, 0, 0, 0);
            a0B = __builtin_amdgcn_mfma_f32_16x16x32_bf16(aH[0][1], bl1B, a0B, 0, 0, 0);
            a1B = __builtin_amdgcn_mfma_f32_16x16x32_bf16(aH[1][1], bl1B, a1B, 0, 0, 0);
            a0A = __builtin_amdgcn_mfma_f32_16x16x32_bf16(aH[0][0], bh0A, a0A, 0, 0, 0);
            a1A = __builtin_amdgcn_mfma_f32_16x16x32_bf16(aH[1][0], bh0A, a1A, 0, 0, 0);
            a0B = __builtin_amdgcn_mfma_f32_16x16x32_bf16(aH[0][0], bh0B, a0B, 0, 0, 0);
            a1B = __builtin_amdgcn_mfma_f32_16x16x32_bf16(aH[1][0], bh0B, a1B, 0, 0, 0);
            a0A = __builtin_amdgcn_mfma_f32_16x16x32_bf16(aH[0][1], bh1A, a0A, 0, 0, 0);
            a1A = __builtin_amdgcn_mfma_f32_16x16x32_bf16(aH[1][1], bh1A, a1A, 0, 0, 0);
            a0B = __builtin_amdgcn_mfma_f32_16x16x32_bf16(aH[0][1], bh1B, a0B, 0, 0, 0);
            a1B = __builtin_amdgcn_mfma_f32_16x16x32_bf16(aH[1][1], bh1B, a1B, 0, 0, 0);
#pragma unroll
            for (int s2 = 0; s2 < 2; ++s2) {
#pragma unroll
                for (int r = 0; r < 4; ++r) {
                    float vA = (s2 ? a1A : a0A)[r];
                    float vB = (s2 ? a1B : a0B)[r];
                    // pack 6-bit j into low mantissa bits (<=64 ULP perturb,
                    // covered by MARGIN_ACC + refine)
                    float kA = __int_as_float((__float_as_int(vA) & ~63) | jA);
                    float kB = __int_as_float((__float_as_int(vB) & ~63) | jB);
                    float hi = fmaxf(kA, kB);
                    float lo = fminf(kA, kB);
                    // exact 2nd-max of {best,best2,kA,kB}, best>=best2:
                    float tm = fminf(best[s2][r], hi);
                    best2[s2][r] = fmaxf(fmaxf(tm, lo), best2[s2][r]);  // max3
                    best[s2][r]  = fmaxf(best[s2][r], hi);
                }
            }
        }
    }

    // Unpack candidate index from key bits.
    int bk[2][4];
#pragma unroll
    for (int s2 = 0; s2 < 2; ++s2)
#pragma unroll
        for (int r = 0; r < 4; ++r)
            bk[s2][r] = ((__float_as_int(best[s2][r]) & 63) << 4) | col;

#pragma unroll
    for (int m = 1; m < 16; m <<= 1) {
#pragma unroll
        for (int s2 = 0; s2 < 2; ++s2) {
#pragma unroll
            for (int r = 0; r < 4; ++r) {
                float ob  = __shfl_xor(best[s2][r], m, 64);
                float ob2 = __shfl_xor(best2[s2][r], m, 64);
                int   obk = __shfl_xor(bk[s2][r], m, 64);
                float nb2 = fmaxf(fmaxf(best2[s2][r], ob2),
                                  fminf(best[s2][r], ob));
                int   nbk = ob > best[s2][r] ? obk
                            : (best[s2][r] > ob ? bk[s2][r]
                                                : min(bk[s2][r], obk));
                best[s2][r]  = fmaxf(best[s2][r], ob);
                best2[s2][r] = nb2;
                bk[s2][r]    = nbk;
            }
        }
    }

    if (col == 0) {
#pragma unroll
        for (int s2 = 0; s2 < 2; ++s2) {
#pragma unroll
            for (int r = 0; r < 4; ++r) {
                int row = rowbase + wave * 32 + s2 * 16 + q * 4 + r;
                idx_ws[row]    = bk[s2][r];
                out_idx_f[row] = (float)bk[s2][r];
                if (best[s2][r] - best2[s2][r] < MARGIN_ACC) {
                    int pos = atomicAdd(flagcnt, 1);
                    if (pos < FLAG_CAP) flaglist[pos] = row;
                }
            }
        }
    }
}

// fp64 rescan of flagged rows (exact); patches idx/out_idx_f before hist.
// Wave-per-row; lane owns 16 contiguous codes; f64 dots via float4 loads;
// 6-step shfl min with lowest-index tiebreak. x^2 dropped (row-constant).
__global__ __launch_bounds__(256) void refine_kernel(
    const float* __restrict__ xt, const float* __restrict__ weight,
    const double* __restrict__ w2d, int* __restrict__ idx_ws,
    float* __restrict__ out_idx_f, const int* __restrict__ flagcnt,
    const int* __restrict__ flaglist) {
    __shared__ float sx[4][64];
    int cnt = *flagcnt;
    if (cnt > FLAG_CAP) cnt = FLAG_CAP;
    int t = threadIdx.x, lane = t & 63, wave = t >> 6;

    for (int r = blockIdx.x * 4 + wave; r < cnt; r += gridDim.x * 4) {
        int row = flaglist[r];
        sx[wave][lane] = xt[(size_t)row * D_DIM + lane];
        // same-wave DS write->read ordering; drain lgkm before the dot loop
        asm volatile("s_waitcnt lgkmcnt(0)" ::: "memory");

        double bd = 1.0e300; int bi = 0;
        int k0 = lane * 16;
#pragma unroll 4
        for (int c = 0; c < 16; ++c) {
            int k = k0 + c;
            const float4* wk4 = (const float4*)(weight + (size_t)k * D_DIM);
            double dot = 0.0;
#pragma unroll
            for (int d4 = 0; d4 < 16; ++d4) {
                float4 wv = wk4[d4];
                dot = fma((double)wv.x, (double)sx[wave][d4 * 4 + 0], dot);
                dot = fma((double)wv.y, (double)sx[wave][d4 * 4 + 1], dot);
                dot = fma((double)wv.z, (double)sx[wave][d4 * 4 + 2], dot);
                dot = fma((double)wv.w, (double)sx[wave][d4 * 4 + 3], dot);
            }
            double dist = w2d[k] - 2.0 * dot;  // x^2 omitted (constant)
            if (dist < bd) { bd = dist; bi = k; }
        }
#pragma unroll
        for (int m = 1; m < 64; m <<= 1) {
            double od = __shfl_xor(bd, m, 64);
            int    oi = __shfl_xor(bi, m, 64);
            if (od < bd || (od == bd && oi < bi)) { bd = od; bi = oi; }
        }
        if (lane == 0 && bi != idx_ws[row]) {
            idx_ws[row]    = bi;
            out_idx_f[row] = (float)bi;
        }
    }
}

// Counting sort, pass 1: per-block LDS histogram of 4096 rows -> histb[b][k].
__global__ __launch_bounds__(256) void hist_kernel(
    const int* __restrict__ idx_ws, int* __restrict__ histb) {
    __shared__ int h[K_CODES];
    int t = threadIdx.x, b = blockIdx.x;
    for (int i = t; i < K_CODES; i += 256) h[i] = 0;
    __syncthreads();
    const int4* idx4 = (const int4*)idx_ws + b * 1024;
#pragma unroll
    for (int i = 0; i < 4; ++i) {
        int4 c = idx4[t + i * 256];
        atomicAdd(&h[c.x], 1); atomicAdd(&h[c.y], 1);
        atomicAdd(&h[c.z], 1); atomicAdd(&h[c.w], 1);
    }
    __syncthreads();
    for (int i = t; i < K_CODES; i += 256) histb[b * K_CODES + i] = h[i];
}

// Pass 2 (1 block, 1024 thr): column prefix over block histograms + global
// exclusive prefix -> cursors (in histb) + goff. Fused Laplace/csn.
__global__ __launch_bounds__(1024) void scan_kernel(
    int* __restrict__ histb, int* __restrict__ goff,
    const float* __restrict__ ema_cs, float* __restrict__ csbuf) {
    __shared__ int pre[K_CODES];
    __shared__ float red[K_CODES];
    int k = threadIdx.x;

    int s = 0;
    for (int b = 0; b < NHB; ++b) {
        int v = histb[b * K_CODES + k];
        histb[b * K_CODES + k] = s;  // local exclusive prefix
        s += v;
    }
    int cnt = s;

    pre[k] = cnt;
    __syncthreads();
    for (int d = 1; d < K_CODES; d <<= 1) {
        int v = (k >= d) ? pre[k - d] : 0;
        __syncthreads();
        if (k >= d) pre[k] += v;
        __syncthreads();
    }
    int base = pre[k] - cnt;
    goff[k] = base;
    if (k == K_CODES - 1) goff[K_CODES] = pre[k];

    for (int b = 0; b < NHB; ++b) histb[b * K_CODES + k] += base;

    float cs = ema_cs[k] * DECAY + OMD * (float)cnt;
    red[k] = cs;
    __syncthreads();
    for (int s2 = 512; s2 > 0; s2 >>= 1) {
        if (k < s2) red[k] += red[k + s2];
        __syncthreads();
    }
    float n = red[0];
    csbuf[k] = (cs + EPS_F) / (n + (float)K_CODES * EPS_F) * n;
}

// Pass 3: scatter row ids into code-sorted order via LDS cursors.
__global__ __launch_bounds__(256) void scatter_kernel(
    const int* __restrict__ idx_ws, const int* __restrict__ histb,
    int* __restrict__ sorted) {
    __shared__ int cur[K_CODES];
    int t = threadIdx.x, b = blockIdx.x;
    for (int i = t; i < K_CODES; i += 256) cur[i] = histb[b * K_CODES + i];
    __syncthreads();
    const int4* idx4 = (const int4*)idx_ws + b * 1024;
#pragma unroll
    for (int i = 0; i < 4; ++i) {
        int4 c = idx4[t + i * 256];
        int r0 = (b * 1024 + t + i * 256) * 4;
        sorted[atomicAdd(&cur[c.x], 1)] = r0 + 0;
        sorted[atomicAdd(&cur[c.y], 1)] = r0 + 1;
        sorted[atomicAdd(&cur[c.z], 1)] = r0 + 2;
        sorted[atomicAdd(&cur[c.w], 1)] = r0 + 3;
    }
}

// Pass 4: one block per code; gather xt rows (coalesced 256B), 2 chains for
// load ILP, LDS tree. Fused EMA+normalize: writes new_w directly.
__global__ __launch_bounds__(256) void dwred_kernel(
    const float* __restrict__ xt, const int* __restrict__ sorted,
    const int* __restrict__ goff, const float* __restrict__ ema_w,
    const float* __restrict__ csbuf, float* __restrict__ new_w) {
    __shared__ int   rows[SEG_CAP];
    __shared__ float red[256];
    int k = blockIdx.x, t = threadIdx.x;
    int base = goff[k];
    int cnt = goff[k + 1] - base;
    int cc = cnt > SEG_CAP ? SEG_CAP : cnt;

    for (int i = t; i < cc; i += 256) rows[i] = sorted[base + i];
    __syncthreads();

    int d = t & 63, sub = t >> 6;
    float a0 = 0.f, a1 = 0.f;
    int i = sub;
    for (; i + 4 < cc; i += 8) {
        a0 += xt[(size_t)rows[i] * D_DIM + d];
        a1 += xt[(size_t)rows[i + 4] * D_DIM + d];
    }
    for (; i < cc; i += 4) a0 += xt[(size_t)rows[i] * D_DIM + d];
    red[t] = a0 + a1;
    __syncthreads();
    if (t < 64) {
        float dwv = red[t] + red[t + 64] + red[t + 128] + red[t + 192];
        new_w[k * D_DIM + t] =
            (ema_w[k * D_DIM + t] * DECAY + OMD * dwv) / csbuf[k];
    }
}

// Gather updated codebook, straight-through output, commitment-loss partials.
// Last block (completion counter) finalizes the loss scalar.
__global__ __launch_bounds__(256) void out_kernel(
    const float* __restrict__ inp, const float* __restrict__ new_w,
    const int* __restrict__ idx_ws, float* __restrict__ out,
    double* __restrict__ loss_acc, int* __restrict__ done_cnt) {
    int row = blockIdx.x * 256 + threadIdx.x;
    int b  = row >> 12;
    int hw = row & (HW - 1);
    const float* xp = inp + (size_t)b * CHW + hw;
    float* op = out + 1 + (size_t)b * CHW + hw;  // out[0] is the loss scalar

    int k = idx_ws[row];
    const float* q = new_w + k * D_DIM;

    float lsum = 0.f;
#pragma unroll
    for (int d = 0; d < D_DIM; ++d) {
        float xv = xp[(size_t)d * HW];
        float qv = q[d];
        float diff = qv - xv;            // stop_gradient(quantized) - x
        lsum = fmaf(diff, diff, lsum);
        op[(size_t)d * HW] = xv + diff;  // x + (quantized - x)
    }

    __shared__ double lred[256];
    lred[threadIdx.x] = (double)lsum;
    __syncthreads();
    for (int s = 128; s > 0; s >>= 1) {
        if (threadIdx.x < s) lred[threadIdx.x] += lred[threadIdx.x + s];
        __syncthreads();
    }
    if (threadIdx.x == 0) {
        atomicAdd(loss_acc, lred[0]);
        __threadfence();  // make our loss add visible before the count add
        int old = atomicAdd(done_cnt, 1);
        if (old == (int)gridDim.x - 1) {
            double v = atomicAdd(loss_acc, 0.0);
            out[0] = (float)(0.25 * (v / (double)N_ELEM));
        }
    }
}

extern "C" void kernel_launch(void* const* d_in, const int* in_sizes, int n_in,
                              void* d_out, int out_size, void* d_ws, size_t ws_size,
                              hipStream_t stream) {
    const float* inp    = (const float*)d_in[0];
    const float* weight = (const float*)d_in[1];
    const float* ema_cs = (const float*)d_in[2];
    const float* ema_w  = (const float*)d_in[3];
    float* out = (float*)d_out;

    char* ws = (char*)d_ws;
    double* loss_acc = (double*)(ws + OFF_LOSS);
    int*    flagcnt  = (int*)(ws + OFF_FLAGCNT);
    int*    done_cnt = (int*)(ws + OFF_DONE);
    float*  w2f      = (float*)(ws + OFF_W2F);
    double* w2d      = (double*)(ws + OFF_W2D);
    float*  csbuf    = (float*)(ws + OFF_CS);
    int*    goff     = (int*)(ws + OFF_GOFF);
    float*  new_w    = (float*)(ws + OFF_NEWW);
    int*    idx_ws   = (int*)(ws + OFF_IDX);
    int*    histb    = (int*)(ws + OFF_HISTB);
    int*    sorted   = (int*)(ws + OFF_SORT);
    int*    flaglist = (int*)(ws + OFF_FLAGS);
    short*  wfrag    = (short*)(ws + OFF_WFRAG);

    float* xt        = out + 1;               // scratch: overwritten by out_kernel
    float* out_idx_f = out + 1 + (size_t)N_ELEM;

    prep_kernel<<<36, 256, 0, stream>>>(weight, wfrag, w2f, w2d, (int*)ws);

    argmin_kernel<<<N_ROWS / BROWS, 256, 0, stream>>>(
        inp, wfrag, w2f, idx_ws, out_idx_f, xt, flagcnt, flaglist);

    refine_kernel<<<512, 256, 0, stream>>>(
        xt, weight, w2d, idx_ws, out_idx_f, flagcnt, flaglist);

    hist_kernel<<<NHB, 256, 0, stream>>>(idx_ws, histb);

    scan_kernel<<<1, 1024, 0, stream>>>(histb, goff, ema_cs, csbuf);

    scatter_kernel<<<NHB, 256, 0, stream>>>(idx_ws, histb, sorted);

    dwred_kernel<<<K_CODES, 256, 0, stream>>>(xt, sorted, goff, ema_w, csbuf, new_w);

    out_kernel<<<N_ROWS / 256, 256, 0, stream>>>(inp, new_w, idx_ws, out,
                                                 loss_acc, done_cnt);
}